// Round 7
// baseline (103.677 us; speedup 1.0000x reference)
//
#include <hip/hip_runtime.h>
#include <hip/hip_bf16.h>

// Problem constants
#define Bn 8
#define Tn 2048
#define En 512
#define Hn 16
#define Dn 32
#define NC 32          // scan chunks
#define CL 64          // chunk length (Tn/NC)
#define TCH 512        // tokens per bilinear block (8 waves x 64)
#define NT (Bn*Tn)     // 16384 tokens
#define INV_DECAY (1.0f/1.2f)

typedef __attribute__((ext_vector_type(8))) short  bf16x8;  // 8 bf16 (4 VGPRs)
typedef __attribute__((ext_vector_type(4))) float  f32x4;
typedef __attribute__((ext_vector_type(8))) unsigned short u16x8;

__device__ __forceinline__ unsigned short f2b(float f) {
    __hip_bfloat16 h = __float2bfloat16(f);   // RNE
    return *reinterpret_cast<unsigned short*>(&h);
}
__device__ __forceinline__ float b2f(unsigned short u) {
    union { unsigned int i; float f; } c; c.i = ((unsigned int)u) << 16; return c.f;
}

// Head-major address: hm[hd][tok][ch], ch in [0,32)
__device__ __forceinline__ size_t hm(int hd, int tok, int ch) {
    return (size_t)hd * ((size_t)NT * Dn) + (size_t)tok * Dn + ch;
}

// ---------------- K0: prep --------------------------------------------------
// blocks 0..255: relayout C f32 -> bf16 per-lane-contiguous image:
//   16B chunk g = ((hd*32 + i)*2 + half)*64 + lane,  lane=(kgrp<<4)|tloc
//   content    = C[hd][k=half*16+tloc][i][kgrp*8 .. +7]
// blocks 256..511: W[k][n] f32 -> Wt[n][k] bf16 (transpose).
__global__ __launch_bounds__(256) void prep_k(const float* __restrict__ C,
                                              unsigned short* __restrict__ Cl,
                                              const float* __restrict__ W,
                                              unsigned short* __restrict__ Wt) {
    __shared__ float tile[32][33];
    if (blockIdx.x < 256) {
        const int g = blockIdx.x * 256 + threadIdx.x;   // 65536 chunks
        const int hd = g >> 12, rem = g & 4095;
        const int i = rem >> 7, half = (rem >> 6) & 1, lane = rem & 63;
        const int tloc = lane & 15, kgrp = lane >> 4;
        const int k = half * 16 + tloc;
        const float* src = C + (size_t)hd * 32768 + (size_t)k * 1024 + i * 32 + kgrp * 8;
        float4 a = reinterpret_cast<const float4*>(src)[0];
        float4 b = reinterpret_cast<const float4*>(src)[1];
        u16x8 st;
        st[0]=f2b(a.x); st[1]=f2b(a.y); st[2]=f2b(a.z); st[3]=f2b(a.w);
        st[4]=f2b(b.x); st[5]=f2b(b.y); st[6]=f2b(b.z); st[7]=f2b(b.w);
        *reinterpret_cast<u16x8*>(Cl + (size_t)g * 8) = st;
    } else {
        const int bid = blockIdx.x - 256;
        const int kb = (bid & 15) * 32, nb = (bid >> 4) * 32;
        const int tx = threadIdx.x & 31, ty = threadIdx.x >> 5;   // ty 0..7
        #pragma unroll
        for (int j = 0; j < 4; j++)
            tile[ty + 8 * j][tx] = W[(size_t)(kb + ty + 8 * j) * En + nb + tx];
        __syncthreads();
        #pragma unroll
        for (int j = 0; j < 4; j++)
            Wt[(size_t)(nb + ty + 8 * j) * En + kb + tx] = f2b(tile[tx][ty + 8 * j]);
    }
}

// ---------------- K1: h = x @ W + b  (bf16 MFMA GEMM, head-major output) -----
__global__ __launch_bounds__(256) void gemm_mfma_k(const float* __restrict__ x,
                                                   const unsigned short* __restrict__ Wt,
                                                   const float* __restrict__ bias,
                                                   unsigned short* __restrict__ h) {
    __shared__ unsigned short As[128][40];
    __shared__ unsigned short Bs[64][40];
    const int m0 = blockIdx.x * 128, n0 = blockIdx.y * 64;
    const int tid = threadIdx.x;
    const int wid = tid >> 6, lane = tid & 63;
    const int tloc = lane & 15, kgrp = lane >> 4;
    const int wr = wid >> 1, wc = wid & 1;

    const int ar = tid >> 1, ah = (tid & 1) * 16;
    const int brr = tid >> 2, bq = (tid & 3) * 8;

    f32x4 acc[4][2] = {};

    for (int k0 = 0; k0 < En; k0 += 32) {
        const float* xp = &x[(size_t)(m0 + ar) * En + k0 + ah];
        float4 a0 = reinterpret_cast<const float4*>(xp)[0];
        float4 a1 = reinterpret_cast<const float4*>(xp)[1];
        float4 a2 = reinterpret_cast<const float4*>(xp)[2];
        float4 a3 = reinterpret_cast<const float4*>(xp)[3];
        u16x8 bv = *reinterpret_cast<const u16x8*>(&Wt[(size_t)(n0 + brr) * En + k0 + bq]);
        __syncthreads();
        u16x8 w0, w1;
        w0[0]=f2b(a0.x); w0[1]=f2b(a0.y); w0[2]=f2b(a0.z); w0[3]=f2b(a0.w);
        w0[4]=f2b(a1.x); w0[5]=f2b(a1.y); w0[6]=f2b(a1.z); w0[7]=f2b(a1.w);
        w1[0]=f2b(a2.x); w1[1]=f2b(a2.y); w1[2]=f2b(a2.z); w1[3]=f2b(a2.w);
        w1[4]=f2b(a3.x); w1[5]=f2b(a3.y); w1[6]=f2b(a3.z); w1[7]=f2b(a3.w);
        *reinterpret_cast<u16x8*>(&As[ar][ah])     = w0;
        *reinterpret_cast<u16x8*>(&As[ar][ah + 8]) = w1;
        *reinterpret_cast<u16x8*>(&Bs[brr][bq])    = bv;
        __syncthreads();

        bf16x8 afr[4], bfr[2];
        #pragma unroll
        for (int m = 0; m < 4; m++)
            afr[m] = *reinterpret_cast<const bf16x8*>(&As[wr * 64 + m * 16 + tloc][kgrp * 8]);
        #pragma unroll
        for (int n = 0; n < 2; n++)
            bfr[n] = *reinterpret_cast<const bf16x8*>(&Bs[wc * 32 + n * 16 + tloc][kgrp * 8]);
        #pragma unroll
        for (int m = 0; m < 4; m++)
            #pragma unroll
            for (int n = 0; n < 2; n++)
                acc[m][n] = __builtin_amdgcn_mfma_f32_16x16x32_bf16(afr[m], bfr[n], acc[m][n], 0, 0, 0);
    }

    #pragma unroll
    for (int n = 0; n < 2; n++) {
        const int col = n0 + wc * 32 + n * 16 + tloc;
        const float bcol = bias[col];
        const int hd = col >> 5, ch = col & 31;
        #pragma unroll
        for (int m = 0; m < 4; m++)
            #pragma unroll
            for (int r = 0; r < 4; r++) {
                const int row = m0 + wr * 64 + m * 16 + kgrp * 4 + r;
                h[hm(hd, row, ch)] = f2b(acc[m][n][r] + bcol);
            }
    }
}

// ---------------- K2a: per-chunk local decayed sums (head-major h) ----------
__global__ __launch_bounds__(512) void scan_local_k(const unsigned short* __restrict__ h,
                                                    float* __restrict__ locals) {
    const int c = blockIdx.x, b = blockIdx.y;
    const int e = threadIdx.x;
    const int hd = e >> 5, ch = e & 31;
    const unsigned short* hp = h + hm(hd, b * Tn + c * CL, ch);
    float s = 0.f;
    for (int t = 0; t < CL; t++) s = (s + b2f(hp[(size_t)t * Dn])) * INV_DECAY;
    locals[(size_t)(b * NC + c) * En + e] = s;
}

// ---------------- K2b: serial prefix over chunks ----------------
__global__ __launch_bounds__(512) void scan_prefix_k(const float* __restrict__ locals,
                                                     float* __restrict__ Acar) {
    const int b = blockIdx.x;
    const int e = threadIdx.x;
    float invRL = 1.f;
    #pragma unroll
    for (int i = 0; i < CL; i++) invRL *= INV_DECAY;
    float A = 0.f;
    for (int c = 0; c < NC; c++) {
        Acar[(size_t)(b * NC + c) * En + e] = A;
        A = A * invRL + locals[(size_t)(b * NC + c) * En + e];
    }
}

// ---------------- K2c: emit S (bf16, head-major) ----------------------------
__global__ __launch_bounds__(512) void scan_emit_k(const unsigned short* __restrict__ h,
                                                   const float* __restrict__ Acar,
                                                   unsigned short* __restrict__ Sg) {
    const int c = blockIdx.x, b = blockIdx.y;
    const int e = threadIdx.x;
    const int hd = e >> 5, ch = e & 31;
    float s = Acar[(size_t)(b * NC + c) * En + e];
    const size_t base = hm(hd, b * Tn + c * CL, ch);
    for (int t = 0; t < CL; t++) {
        Sg[base + (size_t)t * Dn] = f2b(s);
        s = (s + b2f(h[base + (size_t)t * Dn])) * INV_DECAY;
    }
}

// ---------------- K3: bilinear v6 — head-major, contiguous I/O --------------
// Block: 512 thr = 8 waves x 64 tokens, 1 head. C image (64KB) staged linearly
// into LDS (conflict-free reads). h/S slices are 32KB contiguous. In-place y.
__global__ __launch_bounds__(512, 4) void bilinear6_k(unsigned short* __restrict__ hio,
                                                      const unsigned short* __restrict__ Sg,
                                                      const unsigned short* __restrict__ Cl) {
    __shared__ unsigned short Cs[32768];   // 64 KB; aliased as f32 ys[] in epilogue

    const int hd = blockIdx.y;
    const int tid = threadIdx.x;
    const int wid = tid >> 6, lane = tid & 63;
    const int tloc = lane & 15, kgrp = lane >> 4;
    const int j0 = kgrp * 8;
    const int tokens0 = blockIdx.x * TCH + wid * 64;

    // ---- stage C image: straight linear copy, 8 x 16B per thread ----
    {
        const unsigned short* src = Cl + (size_t)hd * 32768;
        #pragma unroll
        for (int p = 0; p < 8; p++) {
            const int c = p * 512 + tid;
            *reinterpret_cast<u16x8*>(&Cs[c * 8]) =
                *reinterpret_cast<const u16x8*>(src + (size_t)c * 8);
        }
    }

    // ---- h rows + S fragments in registers (4 m-tiles x 16 tokens) ----
    u16x8 hreg[4][4];
    float sf[4][8];
    #pragma unroll
    for (int m = 0; m < 4; m++) {
        const int trow = tokens0 + m * 16 + tloc;
        const unsigned short* hrow = hio + hm(hd, trow, 0);
        #pragma unroll
        for (int q = 0; q < 4; q++)
            hreg[m][q] = *reinterpret_cast<const u16x8*>(hrow + q * 8);
        u16x8 sv = *reinterpret_cast<const u16x8*>(Sg + hm(hd, trow, j0));
        #pragma unroll
        for (int e = 0; e < 8; e++) sf[m][e] = b2f(sv[e]);
    }
    __syncthreads();   // C staged

    // ---- main loop: conflict-free LDS B-frags, in-register A-gen ----
    f32x4 acc[4][2] = {};
    #pragma unroll
    for (int i = 0; i < Dn; i++) {
        bf16x8 b0 = *reinterpret_cast<const bf16x8*>(&Cs[(i * 128 + lane) * 8]);
        bf16x8 b1 = *reinterpret_cast<const bf16x8*>(&Cs[(i * 128 + 64 + lane) * 8]);
        #pragma unroll
        for (int m = 0; m < 4; m++) {
            const float hsc = b2f(hreg[m][i >> 3][i & 7]);
            bf16x8 a;
            #pragma unroll
            for (int e = 0; e < 8; e++) a[e] = (short)f2b(hsc * sf[m][e]);
            acc[m][0] = __builtin_amdgcn_mfma_f32_16x16x32_bf16(a, b0, acc[m][0], 0, 0, 0);
            acc[m][1] = __builtin_amdgcn_mfma_f32_16x16x32_bf16(a, b1, acc[m][1], 0, 0, 0);
        }
    }
    __syncthreads();   // all waves done reading Cs

    // ---- epilogue: two-phase transpose via LDS alias, +residual, store ----
    float* ys = reinterpret_cast<float*>(Cs);   // [256][34] f32 = 34.8 KB
    const int wl = wid & 3;
    #pragma unroll
    for (int ph = 0; ph < 2; ph++) {
        if ((wid >> 2) == ph) {
            #pragma unroll
            for (int m = 0; m < 4; m++)
                #pragma unroll
                for (int nt = 0; nt < 2; nt++)
                    #pragma unroll
                    for (int r = 0; r < 4; r++)
                        ys[(wl * 64 + m * 16 + kgrp * 4 + r) * 34 + nt * 16 + tloc] = acc[m][nt][r];
        }
        __syncthreads();
        if ((wid >> 2) == ph) {
            const float* yrow = &ys[(wl * 64 + lane) * 34];
            unsigned short* orow = hio + hm(hd, tokens0 + lane, 0);
            #pragma unroll
            for (int q = 0; q < 4; q++) {
                u16x8 hres = *reinterpret_cast<const u16x8*>(orow + q * 8);
                u16x8 s;
                #pragma unroll
                for (int e2 = 0; e2 < 4; e2++) {
                    float2 v = *reinterpret_cast<const float2*>(yrow + q * 8 + e2 * 2);
                    s[e2 * 2]     = f2b(v.x + b2f(hres[e2 * 2]));
                    s[e2 * 2 + 1] = f2b(v.y + b2f(hres[e2 * 2 + 1]));
                }
                *reinterpret_cast<u16x8*>(orow + q * 8) = s;
            }
        }
        __syncthreads();
    }
}

// ---------------- K4: LayerNorm over E=512 (head-major bf16 in, f32 out) ----
__global__ __launch_bounds__(256) void ln_k(const unsigned short* __restrict__ y,
                                            const float* __restrict__ gamma,
                                            const float* __restrict__ beta,
                                            float* __restrict__ out) {
    const int row = blockIdx.x * 4 + (threadIdx.x >> 6);
    const int lane = threadIdx.x & 63;
    // lane covers channels e = lane*8 .. +7  ->  head lane>>2, ch (lane&3)*8
    u16x8 v = *reinterpret_cast<const u16x8*>(y + hm(lane >> 2, row, (lane & 3) * 8));
    float f[8];
    float s = 0.f, s2 = 0.f;
    #pragma unroll
    for (int e = 0; e < 8; e++) {
        f[e] = b2f(v[e]);
        s += f[e]; s2 += f[e] * f[e];
    }
    #pragma unroll
    for (int off = 1; off < 64; off <<= 1) {
        s  += __shfl_xor(s, off);
        s2 += __shfl_xor(s2, off);
    }
    const float mu = s * (1.f / En);
    const float var = s2 * (1.f / En) - mu * mu;
    const float rs = rsqrtf(var + 1e-3f);
    const int cbase = lane * 8;
    float4 g0 = reinterpret_cast<const float4*>(&gamma[cbase])[0];
    float4 g1 = reinterpret_cast<const float4*>(&gamma[cbase])[1];
    float4 b0 = reinterpret_cast<const float4*>(&beta[cbase])[0];
    float4 b1 = reinterpret_cast<const float4*>(&beta[cbase])[1];
    float4 o0, o1;
    o0.x = (f[0] - mu) * rs * g0.x + b0.x; o0.y = (f[1] - mu) * rs * g0.y + b0.y;
    o0.z = (f[2] - mu) * rs * g0.z + b0.z; o0.w = (f[3] - mu) * rs * g0.w + b0.w;
    o1.x = (f[4] - mu) * rs * g1.x + b1.x; o1.y = (f[5] - mu) * rs * g1.y + b1.y;
    o1.z = (f[6] - mu) * rs * g1.z + b1.z; o1.w = (f[7] - mu) * rs * g1.w + b1.w;
    float* op = out + (size_t)row * En;
    reinterpret_cast<float4*>(op)[lane * 2]     = o0;
    reinterpret_cast<float4*>(op)[lane * 2 + 1] = o1;
}

extern "C" void kernel_launch(void* const* d_in, const int* in_sizes, int n_in,
                              void* d_out, int out_size, void* d_ws, size_t ws_size,
                              hipStream_t stream) {
    const float* x     = (const float*)d_in[0];
    const float* W     = (const float*)d_in[1];
    const float* bias  = (const float*)d_in[2];
    const float* C     = (const float*)d_in[3];
    const float* gamma = (const float*)d_in[4];
    const float* beta  = (const float*)d_in[5];
    float* out = (float*)d_out;

    unsigned short* hb  = (unsigned short*)d_ws;             // head-major h/y
    unsigned short* Sg  = hb + (size_t)NT * En / 1;          // wait: NT*Dn*Hn = NT*En
    Sg = hb + (size_t)Hn * NT * Dn;                          // = 16M elems
    unsigned short* Cl  = Sg + (size_t)Hn * NT * Dn;
    unsigned short* Wt  = Cl + (size_t)Hn * Dn * Dn * Dn;
    float* locals = (float*)(Wt + (size_t)En * En);
    float* Acar   = locals + (size_t)Bn * NC * En;

    prep_k<<<512, 256, 0, stream>>>(C, Cl, W, Wt);
    gemm_mfma_k<<<dim3(NT / 128, En / 64), 256, 0, stream>>>(x, Wt, bias, hb);
    scan_local_k<<<dim3(NC, Bn), 512, 0, stream>>>(hb, locals);
    scan_prefix_k<<<Bn, 512, 0, stream>>>(locals, Acar);
    scan_emit_k<<<dim3(NC, Bn), 512, 0, stream>>>(hb, Acar, Sg);
    bilinear6_k<<<dim3(NT / TCH, Hn), 512, 0, stream>>>(hb, Sg, Cl);
    ln_k<<<NT / 4, 256, 0, stream>>>(hb, gamma, beta, out);
}

// Round 8
// 91.366 us; speedup vs baseline: 1.1347x; 1.1347x over previous
//
#include <hip/hip_runtime.h>
#include <hip/hip_bf16.h>

// Problem constants
#define Bn 8
#define Tn 2048
#define En 512
#define Hn 16
#define Dn 32
#define NC 32          // scan chunks
#define CL 64          // chunk length (Tn/NC)
#define NT (Bn*Tn)     // 16384 tokens
#define INV_DECAY (1.0f/1.2f)

typedef __attribute__((ext_vector_type(8))) short  bf16x8;  // 8 bf16 (4 VGPRs)
typedef __attribute__((ext_vector_type(4))) float  f32x4;
typedef __attribute__((ext_vector_type(8))) unsigned short u16x8;

__device__ __forceinline__ unsigned short f2b(float f) {
    __hip_bfloat16 h = __float2bfloat16(f);   // RNE
    return *reinterpret_cast<unsigned short*>(&h);
}
__device__ __forceinline__ float b2f(unsigned short u) {
    union { unsigned int i; float f; } c; c.i = ((unsigned int)u) << 16; return c.f;
}

// Head-major address: hm[hd][tok][ch], ch in [0,32)
__device__ __forceinline__ size_t hm(int hd, int tok, int ch) {
    return (size_t)hd * ((size_t)NT * Dn) + (size_t)tok * Dn + ch;
}

// ---------------- K0: prep --------------------------------------------------
// blocks 0..255: relayout C f32 -> bf16 per-lane-contiguous image:
//   16B chunk g = ((hd*32 + i)*2 + half)*64 + lane,  lane=(kgrp<<4)|tloc
//   content    = C[hd][k=half*16+tloc][i][kgrp*8 .. +7]
// blocks 256..511: W[k][n] f32 -> Wt[n][k] bf16 (transpose).
__global__ __launch_bounds__(256) void prep_k(const float* __restrict__ C,
                                              unsigned short* __restrict__ Cl,
                                              const float* __restrict__ W,
                                              unsigned short* __restrict__ Wt) {
    __shared__ float tile[32][33];
    if (blockIdx.x < 256) {
        const int g = blockIdx.x * 256 + threadIdx.x;   // 65536 chunks
        const int hd = g >> 12, rem = g & 4095;
        const int i = rem >> 7, half = (rem >> 6) & 1, lane = rem & 63;
        const int tloc = lane & 15, kgrp = lane >> 4;
        const int k = half * 16 + tloc;
        const float* src = C + (size_t)hd * 32768 + (size_t)k * 1024 + i * 32 + kgrp * 8;
        float4 a = reinterpret_cast<const float4*>(src)[0];
        float4 b = reinterpret_cast<const float4*>(src)[1];
        u16x8 st;
        st[0]=f2b(a.x); st[1]=f2b(a.y); st[2]=f2b(a.z); st[3]=f2b(a.w);
        st[4]=f2b(b.x); st[5]=f2b(b.y); st[6]=f2b(b.z); st[7]=f2b(b.w);
        *reinterpret_cast<u16x8*>(Cl + (size_t)g * 8) = st;
    } else {
        const int bid = blockIdx.x - 256;
        const int kb = (bid & 15) * 32, nb = (bid >> 4) * 32;
        const int tx = threadIdx.x & 31, ty = threadIdx.x >> 5;   // ty 0..7
        #pragma unroll
        for (int j = 0; j < 4; j++)
            tile[ty + 8 * j][tx] = W[(size_t)(kb + ty + 8 * j) * En + nb + tx];
        __syncthreads();
        #pragma unroll
        for (int j = 0; j < 4; j++)
            Wt[(size_t)(nb + ty + 8 * j) * En + kb + tx] = f2b(tile[tx][ty + 8 * j]);
    }
}

// ---------------- K1: h = x @ W + b  (bf16 MFMA GEMM, head-major output) -----
__global__ __launch_bounds__(256) void gemm_mfma_k(const float* __restrict__ x,
                                                   const unsigned short* __restrict__ Wt,
                                                   const float* __restrict__ bias,
                                                   unsigned short* __restrict__ h) {
    __shared__ unsigned short As[128][40];
    __shared__ unsigned short Bs[64][40];
    const int m0 = blockIdx.x * 128, n0 = blockIdx.y * 64;
    const int tid = threadIdx.x;
    const int wid = tid >> 6, lane = tid & 63;
    const int tloc = lane & 15, kgrp = lane >> 4;
    const int wr = wid >> 1, wc = wid & 1;

    const int ar = tid >> 1, ah = (tid & 1) * 16;
    const int brr = tid >> 2, bq = (tid & 3) * 8;

    f32x4 acc[4][2] = {};

    for (int k0 = 0; k0 < En; k0 += 32) {
        const float* xp = &x[(size_t)(m0 + ar) * En + k0 + ah];
        float4 a0 = reinterpret_cast<const float4*>(xp)[0];
        float4 a1 = reinterpret_cast<const float4*>(xp)[1];
        float4 a2 = reinterpret_cast<const float4*>(xp)[2];
        float4 a3 = reinterpret_cast<const float4*>(xp)[3];
        u16x8 bv = *reinterpret_cast<const u16x8*>(&Wt[(size_t)(n0 + brr) * En + k0 + bq]);
        __syncthreads();
        u16x8 w0, w1;
        w0[0]=f2b(a0.x); w0[1]=f2b(a0.y); w0[2]=f2b(a0.z); w0[3]=f2b(a0.w);
        w0[4]=f2b(a1.x); w0[5]=f2b(a1.y); w0[6]=f2b(a1.z); w0[7]=f2b(a1.w);
        w1[0]=f2b(a2.x); w1[1]=f2b(a2.y); w1[2]=f2b(a2.z); w1[3]=f2b(a2.w);
        w1[4]=f2b(a3.x); w1[5]=f2b(a3.y); w1[6]=f2b(a3.z); w1[7]=f2b(a3.w);
        *reinterpret_cast<u16x8*>(&As[ar][ah])     = w0;
        *reinterpret_cast<u16x8*>(&As[ar][ah + 8]) = w1;
        *reinterpret_cast<u16x8*>(&Bs[brr][bq])    = bv;
        __syncthreads();

        bf16x8 afr[4], bfr[2];
        #pragma unroll
        for (int m = 0; m < 4; m++)
            afr[m] = *reinterpret_cast<const bf16x8*>(&As[wr * 64 + m * 16 + tloc][kgrp * 8]);
        #pragma unroll
        for (int n = 0; n < 2; n++)
            bfr[n] = *reinterpret_cast<const bf16x8*>(&Bs[wc * 32 + n * 16 + tloc][kgrp * 8]);
        #pragma unroll
        for (int m = 0; m < 4; m++)
            #pragma unroll
            for (int n = 0; n < 2; n++)
                acc[m][n] = __builtin_amdgcn_mfma_f32_16x16x32_bf16(afr[m], bfr[n], acc[m][n], 0, 0, 0);
    }

    #pragma unroll
    for (int n = 0; n < 2; n++) {
        const int col = n0 + wc * 32 + n * 16 + tloc;
        const float bcol = bias[col];
        const int hd = col >> 5, ch = col & 31;
        #pragma unroll
        for (int m = 0; m < 4; m++)
            #pragma unroll
            for (int r = 0; r < 4; r++) {
                const int row = m0 + wr * 64 + m * 16 + kgrp * 4 + r;
                h[hm(hd, row, ch)] = f2b(acc[m][n][r] + bcol);
            }
    }
}

// ---------------- K2a: per-chunk local decayed sums (head-major h) ----------
__global__ __launch_bounds__(512) void scan_local_k(const unsigned short* __restrict__ h,
                                                    float* __restrict__ locals) {
    const int c = blockIdx.x, b = blockIdx.y;
    const int e = threadIdx.x;
    const int hd = e >> 5, ch = e & 31;
    const unsigned short* hp = h + hm(hd, b * Tn + c * CL, ch);
    float s = 0.f;
    for (int t = 0; t < CL; t++) s = (s + b2f(hp[(size_t)t * Dn])) * INV_DECAY;
    locals[(size_t)(b * NC + c) * En + e] = s;
}

// ---------------- K2b: serial prefix over chunks ----------------
__global__ __launch_bounds__(512) void scan_prefix_k(const float* __restrict__ locals,
                                                     float* __restrict__ Acar) {
    const int b = blockIdx.x;
    const int e = threadIdx.x;
    float invRL = 1.f;
    #pragma unroll
    for (int i = 0; i < CL; i++) invRL *= INV_DECAY;
    float A = 0.f;
    for (int c = 0; c < NC; c++) {
        Acar[(size_t)(b * NC + c) * En + e] = A;
        A = A * invRL + locals[(size_t)(b * NC + c) * En + e];
    }
}

// ---------------- K2c: emit S (bf16, head-major) ----------------------------
__global__ __launch_bounds__(512) void scan_emit_k(const unsigned short* __restrict__ h,
                                                   const float* __restrict__ Acar,
                                                   unsigned short* __restrict__ Sg) {
    const int c = blockIdx.x, b = blockIdx.y;
    const int e = threadIdx.x;
    const int hd = e >> 5, ch = e & 31;
    float s = Acar[(size_t)(b * NC + c) * En + e];
    const size_t base = hm(hd, b * Tn + c * CL, ch);
    for (int t = 0; t < CL; t++) {
        Sg[base + (size_t)t * Dn] = f2b(s);
        s = (s + b2f(h[base + (size_t)t * Dn])) * INV_DECAY;
    }
}

// ---------------- K3: bilinear v7 — B from global L2 (no staging) -----------
// Block: 256 thr = 4 waves x 64 tokens, 1 head. B-frags read directly from the
// permuted Cl image (L2/L3-resident, coalesced 1KB/instr). h/S in registers.
// y written into Sg (this block's S range is consumed first). LDS only for the
// per-wave epilogue transpose.
__global__ __launch_bounds__(256) void bilinear7_k(const unsigned short* __restrict__ hg,
                                                   unsigned short* __restrict__ Sio,
                                                   const unsigned short* __restrict__ Cl) {
    __shared__ float ys[4][64][34];   // 34.8 KB -> 4 blocks/CU

    const int hd = blockIdx.y;
    const int tid = threadIdx.x;
    const int wid = tid >> 6, lane = tid & 63;
    const int tloc = lane & 15, kgrp = lane >> 4;
    const int j0 = kgrp * 8;
    const int tokens0 = blockIdx.x * 256 + wid * 64;

    // ---- h rows + S fragments in registers (4 m-tiles x 16 tokens) ----
    u16x8 hreg[4][4];
    float sf[4][8];
    #pragma unroll
    for (int m = 0; m < 4; m++) {
        const int trow = tokens0 + m * 16 + tloc;
        const unsigned short* hrow = hg + hm(hd, trow, 0);
        #pragma unroll
        for (int q = 0; q < 4; q++)
            hreg[m][q] = *reinterpret_cast<const u16x8*>(hrow + q * 8);
        u16x8 sv = *reinterpret_cast<const u16x8*>(Sio + hm(hd, trow, j0));
        #pragma unroll
        for (int e = 0; e < 8; e++) sf[m][e] = b2f(sv[e]);
    }

    // ---- main loop: B direct from global (L2), 8 indep acc chains ----
    f32x4 acc[4][2] = {};
    const bf16x8* bb = reinterpret_cast<const bf16x8*>(Cl + (size_t)hd * 32768);

    #pragma unroll
    for (int i = 0; i < Dn; i++) {
        bf16x8 b0 = bb[i * 128 + lane];
        bf16x8 b1 = bb[i * 128 + 64 + lane];
        #pragma unroll
        for (int m = 0; m < 4; m++) {
            const float hsc = b2f(hreg[m][i >> 3][i & 7]);
            bf16x8 a;
            #pragma unroll
            for (int e = 0; e < 8; e++) a[e] = (short)f2b(hsc * sf[m][e]);
            acc[m][0] = __builtin_amdgcn_mfma_f32_16x16x32_bf16(a, b0, acc[m][0], 0, 0, 0);
            acc[m][1] = __builtin_amdgcn_mfma_f32_16x16x32_bf16(a, b1, acc[m][1], 0, 0, 0);
        }
    }

    // ---- epilogue: per-wave LDS transpose, +residual, coalesced store to Sio ----
    #pragma unroll
    for (int m = 0; m < 4; m++)
        #pragma unroll
        for (int nt = 0; nt < 2; nt++)
            #pragma unroll
            for (int r = 0; r < 4; r++)
                ys[wid][m * 16 + kgrp * 4 + r][nt * 16 + tloc] = acc[m][nt][r];
    __syncthreads();

    {
        const float* yrow = &ys[wid][lane][0];
        const unsigned short* hrow = hg + hm(hd, tokens0 + lane, 0);
        unsigned short* orow = Sio + hm(hd, tokens0 + lane, 0);
        #pragma unroll
        for (int q = 0; q < 4; q++) {
            u16x8 hres = *reinterpret_cast<const u16x8*>(hrow + q * 8);
            u16x8 s;
            #pragma unroll
            for (int e2 = 0; e2 < 4; e2++) {
                float2 v = *reinterpret_cast<const float2*>(yrow + q * 8 + e2 * 2);
                s[e2 * 2]     = f2b(v.x + b2f(hres[e2 * 2]));
                s[e2 * 2 + 1] = f2b(v.y + b2f(hres[e2 * 2 + 1]));
            }
            *reinterpret_cast<u16x8*>(orow + q * 8) = s;
        }
    }
}

// ---------------- K4: LayerNorm over E=512 (head-major bf16 in, f32 out) ----
__global__ __launch_bounds__(256) void ln_k(const unsigned short* __restrict__ y,
                                            const float* __restrict__ gamma,
                                            const float* __restrict__ beta,
                                            float* __restrict__ out) {
    const int row = blockIdx.x * 4 + (threadIdx.x >> 6);
    const int lane = threadIdx.x & 63;
    // lane covers channels e = lane*8 .. +7  ->  head lane>>2, ch (lane&3)*8
    u16x8 v = *reinterpret_cast<const u16x8*>(y + hm(lane >> 2, row, (lane & 3) * 8));
    float f[8];
    float s = 0.f, s2 = 0.f;
    #pragma unroll
    for (int e = 0; e < 8; e++) {
        f[e] = b2f(v[e]);
        s += f[e]; s2 += f[e] * f[e];
    }
    #pragma unroll
    for (int off = 1; off < 64; off <<= 1) {
        s  += __shfl_xor(s, off);
        s2 += __shfl_xor(s2, off);
    }
    const float mu = s * (1.f / En);
    const float var = s2 * (1.f / En) - mu * mu;
    const float rs = rsqrtf(var + 1e-3f);
    const int cbase = lane * 8;
    float4 g0 = reinterpret_cast<const float4*>(&gamma[cbase])[0];
    float4 g1 = reinterpret_cast<const float4*>(&gamma[cbase])[1];
    float4 b0 = reinterpret_cast<const float4*>(&beta[cbase])[0];
    float4 b1 = reinterpret_cast<const float4*>(&beta[cbase])[1];
    float4 o0, o1;
    o0.x = (f[0] - mu) * rs * g0.x + b0.x; o0.y = (f[1] - mu) * rs * g0.y + b0.y;
    o0.z = (f[2] - mu) * rs * g0.z + b0.z; o0.w = (f[3] - mu) * rs * g0.w + b0.w;
    o1.x = (f[4] - mu) * rs * g1.x + b1.x; o1.y = (f[5] - mu) * rs * g1.y + b1.y;
    o1.z = (f[6] - mu) * rs * g1.z + b1.z; o1.w = (f[7] - mu) * rs * g1.w + b1.w;
    float* op = out + (size_t)row * En;
    reinterpret_cast<float4*>(op)[lane * 2]     = o0;
    reinterpret_cast<float4*>(op)[lane * 2 + 1] = o1;
}

extern "C" void kernel_launch(void* const* d_in, const int* in_sizes, int n_in,
                              void* d_out, int out_size, void* d_ws, size_t ws_size,
                              hipStream_t stream) {
    const float* x     = (const float*)d_in[0];
    const float* W     = (const float*)d_in[1];
    const float* bias  = (const float*)d_in[2];
    const float* C     = (const float*)d_in[3];
    const float* gamma = (const float*)d_in[4];
    const float* beta  = (const float*)d_in[5];
    float* out = (float*)d_out;

    unsigned short* hb  = (unsigned short*)d_ws;             // head-major h
    unsigned short* Sg  = hb + (size_t)Hn * NT * Dn;         // head-major S, then y
    unsigned short* Cl  = Sg + (size_t)Hn * NT * Dn;
    unsigned short* Wt  = Cl + (size_t)Hn * Dn * Dn * Dn;
    float* locals = (float*)(Wt + (size_t)En * En);
    float* Acar   = locals + (size_t)Bn * NC * En;

    prep_k<<<512, 256, 0, stream>>>(C, Cl, W, Wt);
    gemm_mfma_k<<<dim3(NT / 128, En / 64), 256, 0, stream>>>(x, Wt, bias, hb);
    scan_local_k<<<dim3(NC, Bn), 512, 0, stream>>>(hb, locals);
    scan_prefix_k<<<Bn, 512, 0, stream>>>(locals, Acar);
    scan_emit_k<<<dim3(NC, Bn), 512, 0, stream>>>(hb, Acar, Sg);
    bilinear7_k<<<dim3(NT / 256, Hn), 256, 0, stream>>>(hb, Sg, Cl);
    ln_k<<<NT / 4, 256, 0, stream>>>(Sg, gamma, beta, out);
}

// Round 9
// 83.548 us; speedup vs baseline: 1.2409x; 1.0936x over previous
//
#include <hip/hip_runtime.h>
#include <hip/hip_bf16.h>

// Problem constants
#define Bn 8
#define Tn 2048
#define En 512
#define Hn 16
#define Dn 32
#define NC 32          // scan chunks
#define CL 64          // chunk length (Tn/NC)
#define NT (Bn*Tn)     // 16384 tokens
#define INV_DECAY (1.0f/1.2f)

typedef __attribute__((ext_vector_type(8))) short  bf16x8;  // 8 bf16 (4 VGPRs)
typedef __attribute__((ext_vector_type(4))) float  f32x4;
typedef __attribute__((ext_vector_type(8))) unsigned short u16x8;

__device__ __forceinline__ unsigned short f2b(float f) {
    __hip_bfloat16 h = __float2bfloat16(f);   // RNE
    return *reinterpret_cast<unsigned short*>(&h);
}
__device__ __forceinline__ float b2f(unsigned short u) {
    union { unsigned int i; float f; } c; c.i = ((unsigned int)u) << 16; return c.f;
}

// Head-major address: hm[hd][tok][ch], ch in [0,32)
__device__ __forceinline__ size_t hm(int hd, int tok, int ch) {
    return (size_t)hd * ((size_t)NT * Dn) + (size_t)tok * Dn + ch;
}

// ---------------- K0: prep --------------------------------------------------
// blocks 0..255: relayout C f32 -> bf16 per-lane-contiguous image:
//   16B chunk g = ((hd*32 + i)*2 + half)*64 + lane,  lane=(kgrp<<4)|tloc
//   content    = C[hd][k=half*16+tloc][i][kgrp*8 .. +7]
// blocks 256..511: W[k][n] f32 -> Wt[n][k] bf16 (transpose).
__global__ __launch_bounds__(256) void prep_k(const float* __restrict__ C,
                                              unsigned short* __restrict__ Cl,
                                              const float* __restrict__ W,
                                              unsigned short* __restrict__ Wt) {
    __shared__ float tile[32][33];
    if (blockIdx.x < 256) {
        const int g = blockIdx.x * 256 + threadIdx.x;   // 65536 chunks
        const int hd = g >> 12, rem = g & 4095;
        const int i = rem >> 7, half = (rem >> 6) & 1, lane = rem & 63;
        const int tloc = lane & 15, kgrp = lane >> 4;
        const int k = half * 16 + tloc;
        const float* src = C + (size_t)hd * 32768 + (size_t)k * 1024 + i * 32 + kgrp * 8;
        float4 a = reinterpret_cast<const float4*>(src)[0];
        float4 b = reinterpret_cast<const float4*>(src)[1];
        u16x8 st;
        st[0]=f2b(a.x); st[1]=f2b(a.y); st[2]=f2b(a.z); st[3]=f2b(a.w);
        st[4]=f2b(b.x); st[5]=f2b(b.y); st[6]=f2b(b.z); st[7]=f2b(b.w);
        *reinterpret_cast<u16x8*>(Cl + (size_t)g * 8) = st;
    } else {
        const int bid = blockIdx.x - 256;
        const int kb = (bid & 15) * 32, nb = (bid >> 4) * 32;
        const int tx = threadIdx.x & 31, ty = threadIdx.x >> 5;   // ty 0..7
        #pragma unroll
        for (int j = 0; j < 4; j++)
            tile[ty + 8 * j][tx] = W[(size_t)(kb + ty + 8 * j) * En + nb + tx];
        __syncthreads();
        #pragma unroll
        for (int j = 0; j < 4; j++)
            Wt[(size_t)(nb + ty + 8 * j) * En + kb + tx] = f2b(tile[tx][ty + 8 * j]);
    }
}

// ---------------- K1: h = x @ W + b  (bf16 MFMA GEMM, head-major output) -----
__global__ __launch_bounds__(256) void gemm_mfma_k(const float* __restrict__ x,
                                                   const unsigned short* __restrict__ Wt,
                                                   const float* __restrict__ bias,
                                                   unsigned short* __restrict__ h) {
    __shared__ unsigned short As[128][40];
    __shared__ unsigned short Bs[64][40];
    const int m0 = blockIdx.x * 128, n0 = blockIdx.y * 64;
    const int tid = threadIdx.x;
    const int wid = tid >> 6, lane = tid & 63;
    const int tloc = lane & 15, kgrp = lane >> 4;
    const int wr = wid >> 1, wc = wid & 1;

    const int ar = tid >> 1, ah = (tid & 1) * 16;
    const int brr = tid >> 2, bq = (tid & 3) * 8;

    f32x4 acc[4][2] = {};

    for (int k0 = 0; k0 < En; k0 += 32) {
        const float* xp = &x[(size_t)(m0 + ar) * En + k0 + ah];
        float4 a0 = reinterpret_cast<const float4*>(xp)[0];
        float4 a1 = reinterpret_cast<const float4*>(xp)[1];
        float4 a2 = reinterpret_cast<const float4*>(xp)[2];
        float4 a3 = reinterpret_cast<const float4*>(xp)[3];
        u16x8 bv = *reinterpret_cast<const u16x8*>(&Wt[(size_t)(n0 + brr) * En + k0 + bq]);
        __syncthreads();
        u16x8 w0, w1;
        w0[0]=f2b(a0.x); w0[1]=f2b(a0.y); w0[2]=f2b(a0.z); w0[3]=f2b(a0.w);
        w0[4]=f2b(a1.x); w0[5]=f2b(a1.y); w0[6]=f2b(a1.z); w0[7]=f2b(a1.w);
        w1[0]=f2b(a2.x); w1[1]=f2b(a2.y); w1[2]=f2b(a2.z); w1[3]=f2b(a2.w);
        w1[4]=f2b(a3.x); w1[5]=f2b(a3.y); w1[6]=f2b(a3.z); w1[7]=f2b(a3.w);
        *reinterpret_cast<u16x8*>(&As[ar][ah])     = w0;
        *reinterpret_cast<u16x8*>(&As[ar][ah + 8]) = w1;
        *reinterpret_cast<u16x8*>(&Bs[brr][bq])    = bv;
        __syncthreads();

        bf16x8 afr[4], bfr[2];
        #pragma unroll
        for (int m = 0; m < 4; m++)
            afr[m] = *reinterpret_cast<const bf16x8*>(&As[wr * 64 + m * 16 + tloc][kgrp * 8]);
        #pragma unroll
        for (int n = 0; n < 2; n++)
            bfr[n] = *reinterpret_cast<const bf16x8*>(&Bs[wc * 32 + n * 16 + tloc][kgrp * 8]);
        #pragma unroll
        for (int m = 0; m < 4; m++)
            #pragma unroll
            for (int n = 0; n < 2; n++)
                acc[m][n] = __builtin_amdgcn_mfma_f32_16x16x32_bf16(afr[m], bfr[n], acc[m][n], 0, 0, 0);
    }

    #pragma unroll
    for (int n = 0; n < 2; n++) {
        const int col = n0 + wc * 32 + n * 16 + tloc;
        const float bcol = bias[col];
        const int hd = col >> 5, ch = col & 31;
        #pragma unroll
        for (int m = 0; m < 4; m++)
            #pragma unroll
            for (int r = 0; r < 4; r++) {
                const int row = m0 + wr * 64 + m * 16 + kgrp * 4 + r;
                h[hm(hd, row, ch)] = f2b(acc[m][n][r] + bcol);
            }
    }
}

// ---------------- K2a: per-chunk local decayed sums (head-major h) ----------
__global__ __launch_bounds__(512) void scan_local_k(const unsigned short* __restrict__ h,
                                                    float* __restrict__ locals) {
    const int c = blockIdx.x, b = blockIdx.y;
    const int e = threadIdx.x;
    const int hd = e >> 5, ch = e & 31;
    const unsigned short* hp = h + hm(hd, b * Tn + c * CL, ch);
    float s = 0.f;
    for (int t = 0; t < CL; t++) s = (s + b2f(hp[(size_t)t * Dn])) * INV_DECAY;
    locals[(size_t)(b * NC + c) * En + e] = s;
}

// ---------------- K2b: serial prefix over chunks ----------------
__global__ __launch_bounds__(512) void scan_prefix_k(const float* __restrict__ locals,
                                                     float* __restrict__ Acar) {
    const int b = blockIdx.x;
    const int e = threadIdx.x;
    float invRL = 1.f;
    #pragma unroll
    for (int i = 0; i < CL; i++) invRL *= INV_DECAY;
    float A = 0.f;
    for (int c = 0; c < NC; c++) {
        Acar[(size_t)(b * NC + c) * En + e] = A;
        A = A * invRL + locals[(size_t)(b * NC + c) * En + e];
    }
}

// ---------------- K2c: emit S (bf16, head-major) ----------------------------
__global__ __launch_bounds__(512) void scan_emit_k(const unsigned short* __restrict__ h,
                                                   const float* __restrict__ Acar,
                                                   unsigned short* __restrict__ Sg) {
    const int c = blockIdx.x, b = blockIdx.y;
    const int e = threadIdx.x;
    const int hd = e >> 5, ch = e & 31;
    float s = Acar[(size_t)(b * NC + c) * En + e];
    const size_t base = hm(hd, b * Tn + c * CL, ch);
    for (int t = 0; t < CL; t++) {
        Sg[base + (size_t)t * Dn] = f2b(s);
        s = (s + b2f(h[base + (size_t)t * Dn])) * INV_DECAY;
    }
}

// ---------------- K3: bilinear v8 — C stationary in regs, K split by wave ---
// Output y^T[k, tok]: A-operand = C2 (stationary A-frags, loaded once),
// B-operand = h*S products (VALU-generated). Wave w owns i in [8w, 8w+8):
// K-slice 256 of the 1024 contraction. Main loop: NO memory ops.
// Block: 256 thr = 4 waves, 64 tokens, 1 head. Partials reduced in LDS.
__global__ __launch_bounds__(256, 3) void bilinear8_k(const unsigned short* __restrict__ hg,
                                                      unsigned short* __restrict__ Sio,
                                                      const unsigned short* __restrict__ Cl) {
    __shared__ float ys[4][64][36];   // 36.9 KB, 144B rows (16B aligned)

    const int hd = blockIdx.y;
    const int tid = threadIdx.x;
    const int wid = tid >> 6, lane = tid & 63;
    const int tloc = lane & 15, kgrp = lane >> 4;
    const int j0 = kgrp * 8;
    const int tokens0 = blockIdx.x * 64;

    // ---- stationary A-frags: C2[k_out = mt*16+tloc][i][j = kgrp*8+e] ----
    // Cl chunk ((hd*32+i)*2+mt)*64 + lane  (16B/lane, coalesced)
    bf16x8 afr[8][2];
    {
        const unsigned short* cb = Cl + (size_t)hd * 32768;
        #pragma unroll
        for (int s = 0; s < 8; s++) {
            const int i = wid * 8 + s;
            #pragma unroll
            for (int mt = 0; mt < 2; mt++)
                afr[s][mt] = *reinterpret_cast<const bf16x8*>(
                    cb + ((size_t)((i * 2 + mt) * 64 + lane) * 8));
        }
    }

    // ---- h slice (this wave's 8 channels) + S fragments, per n-tile ----
    u16x8 hreg[4];
    float sf[4][8];
    #pragma unroll
    for (int nt = 0; nt < 4; nt++) {
        const int trow = tokens0 + nt * 16 + tloc;
        hreg[nt] = *reinterpret_cast<const u16x8*>(hg + hm(hd, trow, wid * 8));
        u16x8 sv = *reinterpret_cast<const u16x8*>(Sio + hm(hd, trow, j0));
        #pragma unroll
        for (int e = 0; e < 8; e++) sf[nt][e] = b2f(sv[e]);
    }

    // ---- main loop: zero memory ops; 8 indep MFMA chains ----
    f32x4 acc[2][4] = {};
    #pragma unroll
    for (int s = 0; s < 8; s++) {
        #pragma unroll
        for (int nt = 0; nt < 4; nt++) {
            const float hsc = b2f(hreg[nt][s]);
            bf16x8 bfrag;
            #pragma unroll
            for (int e = 0; e < 8; e++) bfrag[e] = (short)f2b(hsc * sf[nt][e]);
            acc[0][nt] = __builtin_amdgcn_mfma_f32_16x16x32_bf16(afr[s][0], bfrag, acc[0][nt], 0, 0, 0);
            acc[1][nt] = __builtin_amdgcn_mfma_f32_16x16x32_bf16(afr[s][1], bfrag, acc[1][nt], 0, 0, 0);
        }
    }

    // ---- partials to LDS: acc[mt][nt][r] = y[k=mt*16+kgrp*4+r][tok=nt*16+tloc]
    #pragma unroll
    for (int mt = 0; mt < 2; mt++)
        #pragma unroll
        for (int nt = 0; nt < 4; nt++)
            *reinterpret_cast<f32x4*>(&ys[wid][nt * 16 + tloc][mt * 16 + kgrp * 4]) = acc[mt][nt];
    __syncthreads();

    // ---- reduce 4 partials + residual, coalesced store to Sio ----
    {
        const int token = tid >> 2, q = tid & 3;
        float y[8];
        #pragma unroll
        for (int e = 0; e < 8; e++) y[e] = 0.f;
        #pragma unroll
        for (int w = 0; w < 4; w++) {
            const float* src = &ys[w][token][q * 8];
            #pragma unroll
            for (int e = 0; e < 8; e++) y[e] += src[e];
        }
        const unsigned short* hrow = hg + hm(hd, tokens0 + token, q * 8);
        u16x8 hres = *reinterpret_cast<const u16x8*>(hrow);
        u16x8 st;
        #pragma unroll
        for (int e = 0; e < 8; e++) st[e] = f2b(y[e] + b2f(hres[e]));
        *reinterpret_cast<u16x8*>(Sio + hm(hd, tokens0 + token, q * 8)) = st;
    }
}

// ---------------- K4: LayerNorm over E=512 (head-major bf16 in, f32 out) ----
__global__ __launch_bounds__(256) void ln_k(const unsigned short* __restrict__ y,
                                            const float* __restrict__ gamma,
                                            const float* __restrict__ beta,
                                            float* __restrict__ out) {
    const int row = blockIdx.x * 4 + (threadIdx.x >> 6);
    const int lane = threadIdx.x & 63;
    // lane covers channels e = lane*8 .. +7  ->  head lane>>2, ch (lane&3)*8
    u16x8 v = *reinterpret_cast<const u16x8*>(y + hm(lane >> 2, row, (lane & 3) * 8));
    float f[8];
    float s = 0.f, s2 = 0.f;
    #pragma unroll
    for (int e = 0; e < 8; e++) {
        f[e] = b2f(v[e]);
        s += f[e]; s2 += f[e] * f[e];
    }
    #pragma unroll
    for (int off = 1; off < 64; off <<= 1) {
        s  += __shfl_xor(s, off);
        s2 += __shfl_xor(s2, off);
    }
    const float mu = s * (1.f / En);
    const float var = s2 * (1.f / En) - mu * mu;
    const float rs = rsqrtf(var + 1e-3f);
    const int cbase = lane * 8;
    float4 g0 = reinterpret_cast<const float4*>(&gamma[cbase])[0];
    float4 g1 = reinterpret_cast<const float4*>(&gamma[cbase])[1];
    float4 b0 = reinterpret_cast<const float4*>(&beta[cbase])[0];
    float4 b1 = reinterpret_cast<const float4*>(&beta[cbase])[1];
    float4 o0, o1;
    o0.x = (f[0] - mu) * rs * g0.x + b0.x; o0.y = (f[1] - mu) * rs * g0.y + b0.y;
    o0.z = (f[2] - mu) * rs * g0.z + b0.z; o0.w = (f[3] - mu) * rs * g0.w + b0.w;
    o1.x = (f[4] - mu) * rs * g1.x + b1.x; o1.y = (f[5] - mu) * rs * g1.y + b1.y;
    o1.z = (f[6] - mu) * rs * g1.z + b1.z; o1.w = (f[7] - mu) * rs * g1.w + b1.w;
    float* op = out + (size_t)row * En;
    reinterpret_cast<float4*>(op)[lane * 2]     = o0;
    reinterpret_cast<float4*>(op)[lane * 2 + 1] = o1;
}

extern "C" void kernel_launch(void* const* d_in, const int* in_sizes, int n_in,
                              void* d_out, int out_size, void* d_ws, size_t ws_size,
                              hipStream_t stream) {
    const float* x     = (const float*)d_in[0];
    const float* W     = (const float*)d_in[1];
    const float* bias  = (const float*)d_in[2];
    const float* C     = (const float*)d_in[3];
    const float* gamma = (const float*)d_in[4];
    const float* beta  = (const float*)d_in[5];
    float* out = (float*)d_out;

    unsigned short* hb  = (unsigned short*)d_ws;             // head-major h
    unsigned short* Sg  = hb + (size_t)Hn * NT * Dn;         // head-major S, then y
    unsigned short* Cl  = Sg + (size_t)Hn * NT * Dn;
    unsigned short* Wt  = Cl + (size_t)Hn * Dn * Dn * Dn;
    float* locals = (float*)(Wt + (size_t)En * En);
    float* Acar   = locals + (size_t)Bn * NC * En;

    prep_k<<<512, 256, 0, stream>>>(C, Cl, W, Wt);
    gemm_mfma_k<<<dim3(NT / 128, En / 64), 256, 0, stream>>>(x, Wt, bias, hb);
    scan_local_k<<<dim3(NC, Bn), 512, 0, stream>>>(hb, locals);
    scan_prefix_k<<<Bn, 512, 0, stream>>>(locals, Acar);
    scan_emit_k<<<dim3(NC, Bn), 512, 0, stream>>>(hb, Acar, Sg);
    bilinear8_k<<<dim3(NT / 64, Hn), 256, 0, stream>>>(hb, Sg, Cl);
    ln_k<<<NT / 4, 256, 0, stream>>>(Sg, gamma, beta, out);
}

// Round 10
// 82.295 us; speedup vs baseline: 1.2598x; 1.0152x over previous
//
#include <hip/hip_runtime.h>
#include <hip/hip_bf16.h>

// Problem constants
#define Bn 8
#define Tn 2048
#define En 512
#define Hn 16
#define Dn 32
#define NC 32          // scan chunks
#define CL 64          // chunk length (Tn/NC)
#define NT (Bn*Tn)     // 16384 tokens
#define INV_DECAY (1.0f/1.2f)

typedef __attribute__((ext_vector_type(8))) short  bf16x8;  // 8 bf16 (4 VGPRs)
typedef __attribute__((ext_vector_type(4))) float  f32x4;
typedef __attribute__((ext_vector_type(8))) unsigned short u16x8;

__device__ __forceinline__ unsigned short f2b(float f) {
    __hip_bfloat16 h = __float2bfloat16(f);   // RNE
    return *reinterpret_cast<unsigned short*>(&h);
}
__device__ __forceinline__ float b2f(unsigned short u) {
    union { unsigned int i; float f; } c; c.i = ((unsigned int)u) << 16; return c.f;
}

// (1/1.2)^e, compile-time folded under full unroll
__host__ __device__ constexpr float wpow(int e) {
    float r = 1.f;
    for (int i = 0; i < e; i++) r *= (1.0f / 1.2f);
    return r;
}

// Head-major address: hm[hd][tok][ch], ch in [0,32)
__device__ __forceinline__ size_t hm(int hd, int tok, int ch) {
    return (size_t)hd * ((size_t)NT * Dn) + (size_t)tok * Dn + ch;
}

// ---------------- K0: prep --------------------------------------------------
// blocks 0..255: relayout C f32 -> bf16 per-lane-contiguous image:
//   16B chunk g = ((hd*32 + i)*2 + half)*64 + lane,  lane=(kgrp<<4)|tloc
//   content    = C[hd][k=half*16+tloc][i][kgrp*8 .. +7]
// blocks 256..511: W[k][n] f32 -> Wt[n][k] bf16 (transpose).
__global__ __launch_bounds__(256) void prep_k(const float* __restrict__ C,
                                              unsigned short* __restrict__ Cl,
                                              const float* __restrict__ W,
                                              unsigned short* __restrict__ Wt) {
    __shared__ float tile[32][33];
    if (blockIdx.x < 256) {
        const int g = blockIdx.x * 256 + threadIdx.x;   // 65536 chunks
        const int hd = g >> 12, rem = g & 4095;
        const int i = rem >> 7, half = (rem >> 6) & 1, lane = rem & 63;
        const int tloc = lane & 15, kgrp = lane >> 4;
        const int k = half * 16 + tloc;
        const float* src = C + (size_t)hd * 32768 + (size_t)k * 1024 + i * 32 + kgrp * 8;
        float4 a = reinterpret_cast<const float4*>(src)[0];
        float4 b = reinterpret_cast<const float4*>(src)[1];
        u16x8 st;
        st[0]=f2b(a.x); st[1]=f2b(a.y); st[2]=f2b(a.z); st[3]=f2b(a.w);
        st[4]=f2b(b.x); st[5]=f2b(b.y); st[6]=f2b(b.z); st[7]=f2b(b.w);
        *reinterpret_cast<u16x8*>(Cl + (size_t)g * 8) = st;
    } else {
        const int bid = blockIdx.x - 256;
        const int kb = (bid & 15) * 32, nb = (bid >> 4) * 32;
        const int tx = threadIdx.x & 31, ty = threadIdx.x >> 5;   // ty 0..7
        #pragma unroll
        for (int j = 0; j < 4; j++)
            tile[ty + 8 * j][tx] = W[(size_t)(kb + ty + 8 * j) * En + nb + tx];
        __syncthreads();
        #pragma unroll
        for (int j = 0; j < 4; j++)
            Wt[(size_t)(nb + ty + 8 * j) * En + kb + tx] = f2b(tile[tx][ty + 8 * j]);
    }
}

// ---------------- K1: h = x @ W + b  (bf16 MFMA GEMM + fused local sums) -----
// Epilogue also computes per-chunk decayed sums:
//   locals[cg][col] = sum_t h[t] * (1/1.2)^(64 - t_local),  cg = token/64.
// Thread's 16 rows per column live in chunk cg = blockIdx.x*2 + wr.
__global__ __launch_bounds__(256) void gemm_mfma_k(const float* __restrict__ x,
                                                   const unsigned short* __restrict__ Wt,
                                                   const float* __restrict__ bias,
                                                   unsigned short* __restrict__ h,
                                                   float* __restrict__ locals) {
    __shared__ unsigned short As[128][40];
    __shared__ unsigned short Bs[64][40];
    const int m0 = blockIdx.x * 128, n0 = blockIdx.y * 64;
    const int tid = threadIdx.x;
    const int wid = tid >> 6, lane = tid & 63;
    const int tloc = lane & 15, kgrp = lane >> 4;
    const int wr = wid >> 1, wc = wid & 1;

    const int ar = tid >> 1, ah = (tid & 1) * 16;
    const int brr = tid >> 2, bq = (tid & 3) * 8;

    f32x4 acc[4][2] = {};

    for (int k0 = 0; k0 < En; k0 += 32) {
        const float* xp = &x[(size_t)(m0 + ar) * En + k0 + ah];
        float4 a0 = reinterpret_cast<const float4*>(xp)[0];
        float4 a1 = reinterpret_cast<const float4*>(xp)[1];
        float4 a2 = reinterpret_cast<const float4*>(xp)[2];
        float4 a3 = reinterpret_cast<const float4*>(xp)[3];
        u16x8 bv = *reinterpret_cast<const u16x8*>(&Wt[(size_t)(n0 + brr) * En + k0 + bq]);
        __syncthreads();
        u16x8 w0, w1;
        w0[0]=f2b(a0.x); w0[1]=f2b(a0.y); w0[2]=f2b(a0.z); w0[3]=f2b(a0.w);
        w0[4]=f2b(a1.x); w0[5]=f2b(a1.y); w0[6]=f2b(a1.z); w0[7]=f2b(a1.w);
        w1[0]=f2b(a2.x); w1[1]=f2b(a2.y); w1[2]=f2b(a2.z); w1[3]=f2b(a2.w);
        w1[4]=f2b(a3.x); w1[5]=f2b(a3.y); w1[6]=f2b(a3.z); w1[7]=f2b(a3.w);
        *reinterpret_cast<u16x8*>(&As[ar][ah])     = w0;
        *reinterpret_cast<u16x8*>(&As[ar][ah + 8]) = w1;
        *reinterpret_cast<u16x8*>(&Bs[brr][bq])    = bv;
        __syncthreads();

        bf16x8 afr[4], bfr[2];
        #pragma unroll
        for (int m = 0; m < 4; m++)
            afr[m] = *reinterpret_cast<const bf16x8*>(&As[wr * 64 + m * 16 + tloc][kgrp * 8]);
        #pragma unroll
        for (int n = 0; n < 2; n++)
            bfr[n] = *reinterpret_cast<const bf16x8*>(&Bs[wc * 32 + n * 16 + tloc][kgrp * 8]);
        #pragma unroll
        for (int m = 0; m < 4; m++)
            #pragma unroll
            for (int n = 0; n < 2; n++)
                acc[m][n] = __builtin_amdgcn_mfma_f32_16x16x32_bf16(afr[m], bfr[n], acc[m][n], 0, 0, 0);
    }

    // kgrp factor of the decay weight: 1.2^(4*kgrp)
    const float kmul = (kgrp & 1 ? 2.0736f : 1.f) * (kgrp & 2 ? 4.29981696f : 1.f);
    const int cg = blockIdx.x * 2 + wr;   // global 64-token chunk

    #pragma unroll
    for (int n = 0; n < 2; n++) {
        const int col = n0 + wc * 32 + n * 16 + tloc;
        const float bcol = bias[col];
        const int hd = col >> 5, ch = col & 31;
        float part = 0.f;
        #pragma unroll
        for (int m = 0; m < 4; m++)
            #pragma unroll
            for (int r = 0; r < 4; r++) {
                const int row = m0 + wr * 64 + m * 16 + kgrp * 4 + r;
                const unsigned short hb16 = f2b(acc[m][n][r] + bcol);
                h[hm(hd, row, ch)] = hb16;
                part += b2f(hb16) * (wpow(64 - m * 16 - r) * kmul);
            }
        part += __shfl_xor(part, 16);
        part += __shfl_xor(part, 32);
        if (kgrp == 0) locals[(size_t)cg * En + col] = part;
    }
}

// ---------------- K2: serial prefix over chunks ----------------
__global__ __launch_bounds__(512) void scan_prefix_k(const float* __restrict__ locals,
                                                     float* __restrict__ Acar) {
    const int b = blockIdx.x;
    const int e = threadIdx.x;
    float invRL = 1.f;
    #pragma unroll
    for (int i = 0; i < CL; i++) invRL *= INV_DECAY;
    float A = 0.f;
    for (int c = 0; c < NC; c++) {
        Acar[(size_t)(b * NC + c) * En + e] = A;
        A = A * invRL + locals[(size_t)(b * NC + c) * En + e];
    }
}

// ---------------- K3: bilinear v9 — fused S-recompute, stationary C ---------
// Block: 256 thr = 4 waves, exactly one 64-token scan chunk x 1 head.
// Stage h in LDS; lanes 0..31 serial-scan S from Acar into LDS; v8 main loop
// (wave w owns i in [8w,8w+8), A=C2 stationary, zero memory ops) with h/S
// fragments from LDS. Partials reduced in LDS, +residual, store y.
__global__ __launch_bounds__(256, 3) void bilinear9_k(const unsigned short* __restrict__ hg,
                                                      const float* __restrict__ Acar,
                                                      unsigned short* __restrict__ yb,
                                                      const unsigned short* __restrict__ Cl) {
    __shared__ unsigned short hs[64][40];   // 5 KB (pad-40 rows)
    __shared__ unsigned short Ss[64][40];   // 5 KB
    __shared__ float ys[4][64][36];         // 36.9 KB  -> 46.9 KB total, 3 blk/CU

    const int hd = blockIdx.y;
    const int cg = blockIdx.x;              // global chunk = b*NC + c
    const int tokens0 = cg * 64;
    const int tid = threadIdx.x;
    const int wid = tid >> 6, lane = tid & 63;
    const int tloc = lane & 15, kgrp = lane >> 4;
    const int j0 = kgrp * 8;

    // ---- stationary A-frags (issued early; coalesced 16B/lane) ----
    bf16x8 afr[8][2];
    {
        const unsigned short* cb = Cl + (size_t)hd * 32768;
        #pragma unroll
        for (int s = 0; s < 8; s++) {
            const int i = wid * 8 + s;
            #pragma unroll
            for (int mt = 0; mt < 2; mt++)
                afr[s][mt] = *reinterpret_cast<const bf16x8*>(
                    cb + ((size_t)((i * 2 + mt) * 64 + lane) * 8));
        }
    }

    // ---- stage h chunk (64 tok x 32 ch) into LDS ----
    {
        const int tok = tid >> 2, c8 = (tid & 3) * 8;
        u16x8 v = *reinterpret_cast<const u16x8*>(hg + hm(hd, tokens0 + tok, c8));
        *reinterpret_cast<u16x8*>(&hs[tok][c8]) = v;
    }
    __syncthreads();

    // ---- serial in-block scan: lanes 0..31 produce S (bf16) ----
    if (tid < Dn) {
        float s = Acar[(size_t)cg * En + hd * Dn + tid];
        for (int t = 0; t < 64; t++) {
            Ss[t][tid] = f2b(s);
            s = (s + b2f(hs[t][tid])) * INV_DECAY;
        }
    }
    __syncthreads();

    // ---- per-thread fragments from LDS ----
    u16x8 hreg[4];
    float sf[4][8];
    #pragma unroll
    for (int nt = 0; nt < 4; nt++) {
        const int trow = nt * 16 + tloc;
        hreg[nt] = *reinterpret_cast<const u16x8*>(&hs[trow][wid * 8]);
        u16x8 sv = *reinterpret_cast<const u16x8*>(&Ss[trow][j0]);
        #pragma unroll
        for (int e = 0; e < 8; e++) sf[nt][e] = b2f(sv[e]);
    }

    // ---- main loop: zero memory ops; 8 indep MFMA chains ----
    f32x4 acc[2][4] = {};
    #pragma unroll
    for (int s = 0; s < 8; s++) {
        #pragma unroll
        for (int nt = 0; nt < 4; nt++) {
            const float hsc = b2f(hreg[nt][s]);
            bf16x8 bfrag;
            #pragma unroll
            for (int e = 0; e < 8; e++) bfrag[e] = (short)f2b(hsc * sf[nt][e]);
            acc[0][nt] = __builtin_amdgcn_mfma_f32_16x16x32_bf16(afr[s][0], bfrag, acc[0][nt], 0, 0, 0);
            acc[1][nt] = __builtin_amdgcn_mfma_f32_16x16x32_bf16(afr[s][1], bfrag, acc[1][nt], 0, 0, 0);
        }
    }

    // ---- partials to LDS: acc[mt][nt][r] = y[k=mt*16+kgrp*4+r][tok=nt*16+tloc]
    #pragma unroll
    for (int mt = 0; mt < 2; mt++)
        #pragma unroll
        for (int nt = 0; nt < 4; nt++)
            *reinterpret_cast<f32x4*>(&ys[wid][nt * 16 + tloc][mt * 16 + kgrp * 4]) = acc[mt][nt];
    __syncthreads();

    // ---- reduce 4 partials + residual (from LDS h), coalesced store ----
    {
        const int token = tid >> 2, q = tid & 3;
        float y[8];
        #pragma unroll
        for (int e = 0; e < 8; e++) y[e] = 0.f;
        #pragma unroll
        for (int w = 0; w < 4; w++) {
            const float* src = &ys[w][token][q * 8];
            #pragma unroll
            for (int e = 0; e < 8; e++) y[e] += src[e];
        }
        u16x8 hres = *reinterpret_cast<const u16x8*>(&hs[token][q * 8]);
        u16x8 st;
        #pragma unroll
        for (int e = 0; e < 8; e++) st[e] = f2b(y[e] + b2f(hres[e]));
        *reinterpret_cast<u16x8*>(yb + hm(hd, tokens0 + token, q * 8)) = st;
    }
}

// ---------------- K4: LayerNorm over E=512 (head-major bf16 in, f32 out) ----
__global__ __launch_bounds__(256) void ln_k(const unsigned short* __restrict__ y,
                                            const float* __restrict__ gamma,
                                            const float* __restrict__ beta,
                                            float* __restrict__ out) {
    const int row = blockIdx.x * 4 + (threadIdx.x >> 6);
    const int lane = threadIdx.x & 63;
    // lane covers channels e = lane*8 .. +7  ->  head lane>>2, ch (lane&3)*8
    u16x8 v = *reinterpret_cast<const u16x8*>(y + hm(lane >> 2, row, (lane & 3) * 8));
    float f[8];
    float s = 0.f, s2 = 0.f;
    #pragma unroll
    for (int e = 0; e < 8; e++) {
        f[e] = b2f(v[e]);
        s += f[e]; s2 += f[e] * f[e];
    }
    #pragma unroll
    for (int off = 1; off < 64; off <<= 1) {
        s  += __shfl_xor(s, off);
        s2 += __shfl_xor(s2, off);
    }
    const float mu = s * (1.f / En);
    const float var = s2 * (1.f / En) - mu * mu;
    const float rs = rsqrtf(var + 1e-3f);
    const int cbase = lane * 8;
    float4 g0 = reinterpret_cast<const float4*>(&gamma[cbase])[0];
    float4 g1 = reinterpret_cast<const float4*>(&gamma[cbase])[1];
    float4 b0 = reinterpret_cast<const float4*>(&beta[cbase])[0];
    float4 b1 = reinterpret_cast<const float4*>(&beta[cbase])[1];
    float4 o0, o1;
    o0.x = (f[0] - mu) * rs * g0.x + b0.x; o0.y = (f[1] - mu) * rs * g0.y + b0.y;
    o0.z = (f[2] - mu) * rs * g0.z + b0.z; o0.w = (f[3] - mu) * rs * g0.w + b0.w;
    o1.x = (f[4] - mu) * rs * g1.x + b1.x; o1.y = (f[5] - mu) * rs * g1.y + b1.y;
    o1.z = (f[6] - mu) * rs * g1.z + b1.z; o1.w = (f[7] - mu) * rs * g1.w + b1.w;
    float* op = out + (size_t)row * En;
    reinterpret_cast<float4*>(op)[lane * 2]     = o0;
    reinterpret_cast<float4*>(op)[lane * 2 + 1] = o1;
}

extern "C" void kernel_launch(void* const* d_in, const int* in_sizes, int n_in,
                              void* d_out, int out_size, void* d_ws, size_t ws_size,
                              hipStream_t stream) {
    const float* x     = (const float*)d_in[0];
    const float* W     = (const float*)d_in[1];
    const float* bias  = (const float*)d_in[2];
    const float* C     = (const float*)d_in[3];
    const float* gamma = (const float*)d_in[4];
    const float* beta  = (const float*)d_in[5];
    float* out = (float*)d_out;

    unsigned short* hb  = (unsigned short*)d_ws;             // head-major h
    unsigned short* yb  = hb + (size_t)Hn * NT * Dn;         // head-major y
    unsigned short* Cl  = yb + (size_t)Hn * NT * Dn;
    unsigned short* Wt  = Cl + (size_t)Hn * Dn * Dn * Dn;
    float* locals = (float*)(Wt + (size_t)En * En);
    float* Acar   = locals + (size_t)Bn * NC * En;

    prep_k<<<512, 256, 0, stream>>>(C, Cl, W, Wt);
    gemm_mfma_k<<<dim3(NT / 128, En / 64), 256, 0, stream>>>(x, Wt, bias, hb, locals);
    scan_prefix_k<<<Bn, 512, 0, stream>>>(locals, Acar);
    bilinear9_k<<<dim3(NT / CL, Hn), 256, 0, stream>>>(hb, Acar, yb, Cl);
    ln_k<<<NT / 4, 256, 0, stream>>>(yb, gamma, beta, out);
}

// Round 11
// 81.800 us; speedup vs baseline: 1.2675x; 1.0061x over previous
//
#include <hip/hip_runtime.h>
#include <hip/hip_bf16.h>

// Problem constants
#define Bn 8
#define Tn 2048
#define En 512
#define Hn 16
#define Dn 32
#define NC 32          // scan chunks
#define CL 64          // chunk length (Tn/NC)
#define NT (Bn*Tn)     // 16384 tokens
#define INV_DECAY (1.0f/1.2f)
#define LOG2_INVD (-0.26303440583379383f)   // log2(1/1.2)

typedef __attribute__((ext_vector_type(8))) short  bf16x8;  // 8 bf16 (4 VGPRs)
typedef __attribute__((ext_vector_type(4))) float  f32x4;
typedef __attribute__((ext_vector_type(8))) unsigned short u16x8;

__device__ __forceinline__ unsigned short f2b(float f) {
    __hip_bfloat16 h = __float2bfloat16(f);   // RNE
    return *reinterpret_cast<unsigned short*>(&h);
}
__device__ __forceinline__ float b2f(unsigned short u) {
    union { unsigned int i; float f; } c; c.i = ((unsigned int)u) << 16; return c.f;
}

// (1/1.2)^e, compile-time folded under full unroll
__host__ __device__ constexpr float wpow(int e) {
    float r = 1.f;
    for (int i = 0; i < e; i++) r *= (1.0f / 1.2f);
    return r;
}

// Head-major address: hm[hd][tok][ch], ch in [0,32)
__device__ __forceinline__ size_t hm(int hd, int tok, int ch) {
    return (size_t)hd * ((size_t)NT * Dn) + (size_t)tok * Dn + ch;
}

// ---------------- K0: prep --------------------------------------------------
// blocks 0..255: relayout C f32 -> bf16 per-lane-contiguous image:
//   16B chunk g = ((hd*32 + i)*2 + half)*64 + lane,  lane=(kgrp<<4)|tloc
//   content    = C[hd][k=half*16+tloc][i][kgrp*8 .. +7]
// blocks 256..511: W[k][n] f32 -> Wt[n][k] bf16 (transpose).
__global__ __launch_bounds__(256) void prep_k(const float* __restrict__ C,
                                              unsigned short* __restrict__ Cl,
                                              const float* __restrict__ W,
                                              unsigned short* __restrict__ Wt) {
    __shared__ float tile[32][33];
    if (blockIdx.x < 256) {
        const int g = blockIdx.x * 256 + threadIdx.x;   // 65536 chunks
        const int hd = g >> 12, rem = g & 4095;
        const int i = rem >> 7, half = (rem >> 6) & 1, lane = rem & 63;
        const int tloc = lane & 15, kgrp = lane >> 4;
        const int k = half * 16 + tloc;
        const float* src = C + (size_t)hd * 32768 + (size_t)k * 1024 + i * 32 + kgrp * 8;
        float4 a = reinterpret_cast<const float4*>(src)[0];
        float4 b = reinterpret_cast<const float4*>(src)[1];
        u16x8 st;
        st[0]=f2b(a.x); st[1]=f2b(a.y); st[2]=f2b(a.z); st[3]=f2b(a.w);
        st[4]=f2b(b.x); st[5]=f2b(b.y); st[6]=f2b(b.z); st[7]=f2b(b.w);
        *reinterpret_cast<u16x8*>(Cl + (size_t)g * 8) = st;
    } else {
        const int bid = blockIdx.x - 256;
        const int kb = (bid & 15) * 32, nb = (bid >> 4) * 32;
        const int tx = threadIdx.x & 31, ty = threadIdx.x >> 5;   // ty 0..7
        #pragma unroll
        for (int j = 0; j < 4; j++)
            tile[ty + 8 * j][tx] = W[(size_t)(kb + ty + 8 * j) * En + nb + tx];
        __syncthreads();
        #pragma unroll
        for (int j = 0; j < 4; j++)
            Wt[(size_t)(nb + ty + 8 * j) * En + kb + tx] = f2b(tile[tx][ty + 8 * j]);
    }
}

// ---------------- K1: h = x @ W + b  (bf16 MFMA GEMM + fused local sums) -----
__global__ __launch_bounds__(256) void gemm_mfma_k(const float* __restrict__ x,
                                                   const unsigned short* __restrict__ Wt,
                                                   const float* __restrict__ bias,
                                                   unsigned short* __restrict__ h,
                                                   float* __restrict__ locals) {
    __shared__ unsigned short As[128][40];
    __shared__ unsigned short Bs[64][40];
    const int m0 = blockIdx.x * 128, n0 = blockIdx.y * 64;
    const int tid = threadIdx.x;
    const int wid = tid >> 6, lane = tid & 63;
    const int tloc = lane & 15, kgrp = lane >> 4;
    const int wr = wid >> 1, wc = wid & 1;

    const int ar = tid >> 1, ah = (tid & 1) * 16;
    const int brr = tid >> 2, bq = (tid & 3) * 8;

    f32x4 acc[4][2] = {};

    for (int k0 = 0; k0 < En; k0 += 32) {
        const float* xp = &x[(size_t)(m0 + ar) * En + k0 + ah];
        float4 a0 = reinterpret_cast<const float4*>(xp)[0];
        float4 a1 = reinterpret_cast<const float4*>(xp)[1];
        float4 a2 = reinterpret_cast<const float4*>(xp)[2];
        float4 a3 = reinterpret_cast<const float4*>(xp)[3];
        u16x8 bv = *reinterpret_cast<const u16x8*>(&Wt[(size_t)(n0 + brr) * En + k0 + bq]);
        __syncthreads();
        u16x8 w0, w1;
        w0[0]=f2b(a0.x); w0[1]=f2b(a0.y); w0[2]=f2b(a0.z); w0[3]=f2b(a0.w);
        w0[4]=f2b(a1.x); w0[5]=f2b(a1.y); w0[6]=f2b(a1.z); w0[7]=f2b(a1.w);
        w1[0]=f2b(a2.x); w1[1]=f2b(a2.y); w1[2]=f2b(a2.z); w1[3]=f2b(a2.w);
        w1[4]=f2b(a3.x); w1[5]=f2b(a3.y); w1[6]=f2b(a3.z); w1[7]=f2b(a3.w);
        *reinterpret_cast<u16x8*>(&As[ar][ah])     = w0;
        *reinterpret_cast<u16x8*>(&As[ar][ah + 8]) = w1;
        *reinterpret_cast<u16x8*>(&Bs[brr][bq])    = bv;
        __syncthreads();

        bf16x8 afr[4], bfr[2];
        #pragma unroll
        for (int m = 0; m < 4; m++)
            afr[m] = *reinterpret_cast<const bf16x8*>(&As[wr * 64 + m * 16 + tloc][kgrp * 8]);
        #pragma unroll
        for (int n = 0; n < 2; n++)
            bfr[n] = *reinterpret_cast<const bf16x8*>(&Bs[wc * 32 + n * 16 + tloc][kgrp * 8]);
        #pragma unroll
        for (int m = 0; m < 4; m++)
            #pragma unroll
            for (int n = 0; n < 2; n++)
                acc[m][n] = __builtin_amdgcn_mfma_f32_16x16x32_bf16(afr[m], bfr[n], acc[m][n], 0, 0, 0);
    }

    const float kmul = (kgrp & 1 ? 2.0736f : 1.f) * (kgrp & 2 ? 4.29981696f : 1.f);
    const int cg = blockIdx.x * 2 + wr;   // global 64-token chunk

    #pragma unroll
    for (int n = 0; n < 2; n++) {
        const int col = n0 + wc * 32 + n * 16 + tloc;
        const float bcol = bias[col];
        const int hd = col >> 5, ch = col & 31;
        float part = 0.f;
        #pragma unroll
        for (int m = 0; m < 4; m++)
            #pragma unroll
            for (int r = 0; r < 4; r++) {
                const int row = m0 + wr * 64 + m * 16 + kgrp * 4 + r;
                const unsigned short hb16 = f2b(acc[m][n][r] + bcol);
                h[hm(hd, row, ch)] = hb16;
                part += b2f(hb16) * (wpow(64 - m * 16 - r) * kmul);
            }
        part += __shfl_xor(part, 16);
        part += __shfl_xor(part, 32);
        if (kgrp == 0) locals[(size_t)cg * En + col] = part;
    }
}

// ---------------- K2: serial prefix over chunks ----------------
__global__ __launch_bounds__(512) void scan_prefix_k(const float* __restrict__ locals,
                                                     float* __restrict__ Acar) {
    const int b = blockIdx.x;
    const int e = threadIdx.x;
    float invRL = 1.f;
    #pragma unroll
    for (int i = 0; i < CL; i++) invRL *= INV_DECAY;
    float A = 0.f;
    for (int c = 0; c < NC; c++) {
        Acar[(size_t)(b * NC + c) * En + e] = A;
        A = A * invRL + locals[(size_t)(b * NC + c) * En + e];
    }
}

// ---------------- K3: bilinear v10 — KS wave-parallel scan, resident C ------
// Block: 256 thr = 4 waves, one 64-token chunk x 1 head.
// Wave w: stationary A-frags = C2 slice i in [8w,8w+8) (64 VGPR, kept resident
// via launch_bounds(256,2)); Kogge-Stone decayed prefix (lane=token, 8 ch/wave)
// replaces the serial scan. Main loop: zero memory ops.
__global__ __launch_bounds__(256, 2) void bilinear10_k(const unsigned short* __restrict__ hg,
                                                       const float* __restrict__ Acar,
                                                       unsigned short* __restrict__ yb,
                                                       const unsigned short* __restrict__ Cl) {
    __shared__ unsigned short hs[64][40];   // 5 KB
    __shared__ unsigned short Ss[64][40];   // 5 KB
    __shared__ float ys[4][64][33];         // 33.8 KB, (row+col)%32 banking

    const int hd = blockIdx.y;
    const int cg = blockIdx.x;              // global chunk = b*NC + c
    const int tokens0 = cg * 64;
    const int tid = threadIdx.x;
    const int wid = tid >> 6, lane = tid & 63;
    const int tloc = lane & 15, kgrp = lane >> 4;
    const int j0 = kgrp * 8;
    const int c0 = wid * 8;

    // ---- stationary A-frags (coalesced 16B/lane, issued first) ----
    bf16x8 afr[8][2];
    {
        const unsigned short* cb = Cl + (size_t)hd * 32768;
        #pragma unroll
        for (int s = 0; s < 8; s++) {
            const int i = wid * 8 + s;
            #pragma unroll
            for (int mt = 0; mt < 2; mt++)
                afr[s][mt] = *reinterpret_cast<const bf16x8*>(
                    cb + ((size_t)((i * 2 + mt) * 64 + lane) * 8));
        }
    }

    // ---- carry for this wave's 8 channels (wave-uniform loads) ----
    float Ac[8];
    #pragma unroll
    for (int e = 0; e < 8; e++)
        Ac[e] = Acar[(size_t)cg * En + hd * Dn + c0 + e];

    // ---- stage h chunk (64 tok x 32 ch) into LDS ----
    {
        const int tok = tid >> 2, c8 = (tid & 3) * 8;
        *reinterpret_cast<u16x8*>(&hs[tok][c8]) =
            *reinterpret_cast<const u16x8*>(hg + hm(hd, tokens0 + tok, c8));
    }
    __syncthreads();

    // ---- Kogge-Stone decayed prefix: lane = token, wave w owns channels c0..c0+7
    {
        float P[8];
        u16x8 hv = *reinterpret_cast<const u16x8*>(&hs[lane][c0]);
        #pragma unroll
        for (int e = 0; e < 8; e++) P[e] = b2f(hv[e]);
        #pragma unroll
        for (int k = 0; k < 6; k++) {
            const int dlt = 1 << k;
            const float wk = wpow(1 << k);
            #pragma unroll
            for (int e = 0; e < 8; e++) {
                float o = __shfl_up(P[e], dlt, 64);
                P[e] += (lane >= dlt) ? wk * o : 0.f;
            }
        }
        // S_t = Ac * d^t + d * P_{t-1}
        const float dt = exp2f((float)lane * LOG2_INVD);
        u16x8 sst;
        #pragma unroll
        for (int e = 0; e < 8; e++) {
            float pm1 = __shfl_up(P[e], 1, 64);
            if (lane == 0) pm1 = 0.f;
            sst[e] = f2b(Ac[e] * dt + INV_DECAY * pm1);
        }
        *reinterpret_cast<u16x8*>(&Ss[lane][c0]) = sst;
    }
    __syncthreads();

    // ---- per-thread fragments from LDS ----
    u16x8 hreg[4];
    float sf[4][8];
    #pragma unroll
    for (int nt = 0; nt < 4; nt++) {
        const int trow = nt * 16 + tloc;
        hreg[nt] = *reinterpret_cast<const u16x8*>(&hs[trow][c0]);
        u16x8 sv = *reinterpret_cast<const u16x8*>(&Ss[trow][j0]);
        #pragma unroll
        for (int e = 0; e < 8; e++) sf[nt][e] = b2f(sv[e]);
    }

    // ---- main loop: zero memory ops; 8 indep MFMA chains ----
    f32x4 acc[2][4] = {};
    #pragma unroll
    for (int s = 0; s < 8; s++) {
        #pragma unroll
        for (int nt = 0; nt < 4; nt++) {
            const float hsc = b2f(hreg[nt][s]);
            bf16x8 bfrag;
            #pragma unroll
            for (int e = 0; e < 8; e++) bfrag[e] = (short)f2b(hsc * sf[nt][e]);
            acc[0][nt] = __builtin_amdgcn_mfma_f32_16x16x32_bf16(afr[s][0], bfrag, acc[0][nt], 0, 0, 0);
            acc[1][nt] = __builtin_amdgcn_mfma_f32_16x16x32_bf16(afr[s][1], bfrag, acc[1][nt], 0, 0, 0);
        }
    }

    // ---- partials to LDS (scalar, ~2-way banks) ----
    #pragma unroll
    for (int mt = 0; mt < 2; mt++)
        #pragma unroll
        for (int nt = 0; nt < 4; nt++)
            #pragma unroll
            for (int r = 0; r < 4; r++)
                ys[wid][nt * 16 + tloc][mt * 16 + kgrp * 4 + r] = acc[mt][nt][r];
    __syncthreads();

    // ---- reduce 4 partials + residual (LDS h), coalesced store ----
    {
        const int token = tid >> 2, q = tid & 3;
        float y[8];
        #pragma unroll
        for (int e = 0; e < 8; e++) y[e] = 0.f;
        #pragma unroll
        for (int w = 0; w < 4; w++) {
            #pragma unroll
            for (int e = 0; e < 8; e++) y[e] += ys[w][token][q * 8 + e];
        }
        u16x8 hres = *reinterpret_cast<const u16x8*>(&hs[token][q * 8]);
        u16x8 st;
        #pragma unroll
        for (int e = 0; e < 8; e++) st[e] = f2b(y[e] + b2f(hres[e]));
        *reinterpret_cast<u16x8*>(yb + hm(hd, tokens0 + token, q * 8)) = st;
    }
}

// ---------------- K4: LayerNorm over E=512 (head-major bf16 in, f32 out) ----
__global__ __launch_bounds__(256) void ln_k(const unsigned short* __restrict__ y,
                                            const float* __restrict__ gamma,
                                            const float* __restrict__ beta,
                                            float* __restrict__ out) {
    const int row = blockIdx.x * 4 + (threadIdx.x >> 6);
    const int lane = threadIdx.x & 63;
    u16x8 v = *reinterpret_cast<const u16x8*>(y + hm(lane >> 2, row, (lane & 3) * 8));
    float f[8];
    float s = 0.f, s2 = 0.f;
    #pragma unroll
    for (int e = 0; e < 8; e++) {
        f[e] = b2f(v[e]);
        s += f[e]; s2 += f[e] * f[e];
    }
    #pragma unroll
    for (int off = 1; off < 64; off <<= 1) {
        s  += __shfl_xor(s, off);
        s2 += __shfl_xor(s2, off);
    }
    const float mu = s * (1.f / En);
    const float var = s2 * (1.f / En) - mu * mu;
    const float rs = rsqrtf(var + 1e-3f);
    const int cbase = lane * 8;
    float4 g0 = reinterpret_cast<const float4*>(&gamma[cbase])[0];
    float4 g1 = reinterpret_cast<const float4*>(&gamma[cbase])[1];
    float4 b0 = reinterpret_cast<const float4*>(&beta[cbase])[0];
    float4 b1 = reinterpret_cast<const float4*>(&beta[cbase])[1];
    float4 o0, o1;
    o0.x = (f[0] - mu) * rs * g0.x + b0.x; o0.y = (f[1] - mu) * rs * g0.y + b0.y;
    o0.z = (f[2] - mu) * rs * g0.z + b0.z; o0.w = (f[3] - mu) * rs * g0.w + b0.w;
    o1.x = (f[4] - mu) * rs * g1.x + b1.x; o1.y = (f[5] - mu) * rs * g1.y + b1.y;
    o1.z = (f[6] - mu) * rs * g1.z + b1.z; o1.w = (f[7] - mu) * rs * g1.w + b1.w;
    float* op = out + (size_t)row * En;
    reinterpret_cast<float4*>(op)[lane * 2]     = o0;
    reinterpret_cast<float4*>(op)[lane * 2 + 1] = o1;
}

extern "C" void kernel_launch(void* const* d_in, const int* in_sizes, int n_in,
                              void* d_out, int out_size, void* d_ws, size_t ws_size,
                              hipStream_t stream) {
    const float* x     = (const float*)d_in[0];
    const float* W     = (const float*)d_in[1];
    const float* bias  = (const float*)d_in[2];
    const float* C     = (const float*)d_in[3];
    const float* gamma = (const float*)d_in[4];
    const float* beta  = (const float*)d_in[5];
    float* out = (float*)d_out;

    unsigned short* hb  = (unsigned short*)d_ws;             // head-major h
    unsigned short* yb  = hb + (size_t)Hn * NT * Dn;         // head-major y
    unsigned short* Cl  = yb + (size_t)Hn * NT * Dn;
    unsigned short* Wt  = Cl + (size_t)Hn * Dn * Dn * Dn;
    float* locals = (float*)(Wt + (size_t)En * En);
    float* Acar   = locals + (size_t)Bn * NC * En;

    prep_k<<<512, 256, 0, stream>>>(C, Cl, W, Wt);
    gemm_mfma_k<<<dim3(NT / 128, En / 64), 256, 0, stream>>>(x, Wt, bias, hb, locals);
    scan_prefix_k<<<Bn, 512, 0, stream>>>(locals, Acar);
    bilinear10_k<<<dim3(NT / CL, Hn), 256, 0, stream>>>(hb, Acar, yb, Cl);
    ln_k<<<NT / 4, 256, 0, stream>>>(yb, gamma, beta, out);
}